// Round 8
// baseline (103.287 us; speedup 1.0000x reference)
//
#include <hip/hip_runtime.h>

#define NH 8
#define LQ 384
#define LK 384
#define BS 2

// ---------------- Kernel 1: Ek = exp(2*(kW+b1)), layout [bh][e4][k][4] ----------------
__global__ __launch_bounds__(256) void pre_ek_kernel(
    const float* __restrict__ kin, const float* __restrict__ w1,
    const float* __restrict__ b1, float* __restrict__ ws)
{
    __shared__ float tile[32][65];
    const int bid = blockIdx.x;
    const int bh = bid / 12, kt = bid % 12;
    const int b = bh >> 3, h = bh & 7;
    const int k0 = kt * 32;
    const int lane = threadIdx.x & 63, w = threadIdx.x >> 6;

    float w1c[32];
    const float* w1p = w1 + (size_t)(h * 64 + 32) * 64 + lane;
    #pragma unroll
    for (int d = 0; d < 32; ++d) w1c[d] = w1p[d * 64];
    const float bv = b1[h * 64 + lane];

    #pragma unroll
    for (int s = 0; s < 8; ++s) {
        int kr = w * 8 + s;
        const float* krow = kin + ((size_t)(b * LK + k0 + kr)) * (NH * 32) + h * 32;
        float acc = bv;
        #pragma unroll
        for (int d = 0; d < 32; ++d) acc = __builtin_fmaf(krow[d], w1c[d], acc);
        tile[kr][lane] = __expf(acc + acc);
    }
    __syncthreads();
    #pragma unroll
    for (int r = 0; r < 2; ++r) {
        int f = threadIdx.x + r * 256;
        int e4 = f >> 5, k32 = f & 31;
        float4 o;
        o.x = tile[k32][e4 * 4 + 0];
        o.y = tile[k32][e4 * 4 + 1];
        o.z = tile[k32][e4 * 4 + 2];
        o.w = tile[k32][e4 * 4 + 3];
        ((float4*)ws)[((size_t)(bh * 16 + e4)) * LK + k0 + k32] = o;
    }
}

// ---------------- Kernel 2: q-tile=4, wave=(row-pair, k-half); forced 6 waves/SIMD ----------------
// grid = 1536 (6 blocks/CU). 3 barriers total; one-shot (m,u) softmax exchange.
__global__ __launch_bounds__(256, 6) void attn_kernel(
    const float* __restrict__ qin, const float* __restrict__ vin,
    const int* __restrict__ qlens, const int* __restrict__ klens,
    const float* __restrict__ w1, const float* __restrict__ w2g,
    const float* __restrict__ ws,
    float* __restrict__ outg, float* __restrict__ attg)
{
    __shared__ __align__(16) float eqs[4 * 64];        // 1KB
    __shared__ __align__(16) float att_h[4][2 * 192];  // 6KB wave-private att halves
    __shared__ __align__(16) float w2s[64];
    __shared__ float2 smu[2][2][2];                    // [pair][row][half] (max, sum)
    __shared__ __align__(16) float4 pvp[2][2][2][8];   // [pair][half][row][dvq]

    const int tid = threadIdx.x, wave = tid >> 6, lane = tid & 63;
    const int pair = wave >> 1, hh = wave & 1;
    const int bh = blockIdx.x / 96, tile = blockIdx.x % 96;
    const int b = bh >> 3, h = bh & 7;
    const int q0 = tile * 4;
    const int klen = klens[b], qlen = qlens[b];

    // ---- Eq: wave w computes row w (e = lane) ----
    {
        const float* w1p = w1 + (size_t)h * 64 * 64 + lane;
        const float* qp  = qin + ((size_t)(b * LQ + q0 + wave)) * (NH * 32) + h * 32;
        float a = 0.f;
        #pragma unroll
        for (int d = 0; d < 32; ++d) a = __builtin_fmaf(qp[d], w1p[d * 64], a);
        eqs[wave * 64 + lane] = __expf(a + a);
        if (wave == 0) w2s[lane] = w2g[h * 64 + lane];
    }
    __syncthreads();   // (1)

    // ---- score: k = hh*192 + c*64 + lane; reg-dbuf on kv ----
    float sc0[3] = {0.f, 0.f, 0.f};
    float sc1[3] = {0.f, 0.f, 0.f};
    const float4* ekq  = (const float4*)ws + ((size_t)bh * 16) * LK + hh * 192 + lane;
    const float4* eq0p = (const float4*)(eqs + (2 * pair) * 64);
    const float4* eq1p = (const float4*)(eqs + (2 * pair + 1) * 64);
    const float4* w2p  = (const float4*)w2s;

    float4 kv[3];
    #pragma unroll
    for (int c = 0; c < 3; ++c) kv[c] = ekq[c * 64];

    #pragma unroll
    for (int e4 = 0; e4 < 16; ++e4) {
        float4 nkv[3];
        if (e4 < 15) {
            const float4* np = ekq + (size_t)(e4 + 1) * LK;
            #pragma unroll
            for (int c = 0; c < 3; ++c) nkv[c] = np[c * 64];
        }
        float4 e0 = eq0p[e4];
        float4 e1 = eq1p[e4];
        float4 wv = w2p[e4];
        #pragma unroll
        for (int c = 0; c < 3; ++c) {
            float4 kq = kv[c];
            {   // row 0: sum_u w_u/(1+Eq_u*Ek_u), one rcp per 4 terms
                float t0 = __builtin_fmaf(e0.x, kq.x, 1.f);
                float t1 = __builtin_fmaf(e0.y, kq.y, 1.f);
                float t2 = __builtin_fmaf(e0.z, kq.z, 1.f);
                float t3 = __builtin_fmaf(e0.w, kq.w, 1.f);
                float p12 = t0 * t1, p34 = t2 * t3;
                float n12 = wv.x * t1; n12 = __builtin_fmaf(wv.y, t0, n12);
                float n34 = wv.z * t3; n34 = __builtin_fmaf(wv.w, t2, n34);
                float num = n12 * p34; num = __builtin_fmaf(n34, p12, num);
                sc0[c] = __builtin_fmaf(num, __builtin_amdgcn_rcpf(p12 * p34), sc0[c]);
            }
            {   // row 1
                float t0 = __builtin_fmaf(e1.x, kq.x, 1.f);
                float t1 = __builtin_fmaf(e1.y, kq.y, 1.f);
                float t2 = __builtin_fmaf(e1.z, kq.z, 1.f);
                float t3 = __builtin_fmaf(e1.w, kq.w, 1.f);
                float p12 = t0 * t1, p34 = t2 * t3;
                float n12 = wv.x * t1; n12 = __builtin_fmaf(wv.y, t0, n12);
                float n34 = wv.z * t3; n34 = __builtin_fmaf(wv.w, t2, n34);
                float num = n12 * p34; num = __builtin_fmaf(n34, p12, num);
                sc1[c] = __builtin_fmaf(num, __builtin_amdgcn_rcpf(p12 * p34), sc1[c]);
            }
        }
        if (e4 < 15) {
            #pragma unroll
            for (int c = 0; c < 3; ++c) kv[c] = nkv[c];
        }
    }

    // ---- local softmax stats + single exchange barrier ----
    float s0_[3], s1_[3];
    float m0 = -3.4e38f, m1 = -3.4e38f;
    #pragma unroll
    for (int c = 0; c < 3; ++c) {
        int kk = hh * 192 + c * 64 + lane;
        s0_[c] = (kk < klen) ? -2.0f * sc0[c] : -3.4e38f;
        s1_[c] = (kk < klen) ? -2.0f * sc1[c] : -3.4e38f;
        m0 = fmaxf(m0, s0_[c]);
        m1 = fmaxf(m1, s1_[c]);
    }
    #pragma unroll
    for (int off = 32; off >= 1; off >>= 1) {
        m0 = fmaxf(m0, __shfl_xor(m0, off));
        m1 = fmaxf(m1, __shfl_xor(m1, off));
    }
    float e0_[3], e1_[3];
    float u0 = 0.f, u1 = 0.f;
    #pragma unroll
    for (int c = 0; c < 3; ++c) {
        int kk = hh * 192 + c * 64 + lane;
        e0_[c] = (kk < klen) ? __expf(s0_[c] - m0) : 0.f;
        e1_[c] = (kk < klen) ? __expf(s1_[c] - m1) : 0.f;
        u0 += e0_[c];
        u1 += e1_[c];
    }
    #pragma unroll
    for (int off = 32; off >= 1; off >>= 1) {
        u0 += __shfl_xor(u0, off);
        u1 += __shfl_xor(u1, off);
    }
    if (lane == 0) {
        smu[pair][0][hh] = make_float2(m0, u0);
        smu[pair][1][hh] = make_float2(m1, u1);
    }
    __syncthreads();   // (2)
    float f0, f1;
    {
        float2 a = smu[pair][0][0], c2 = smu[pair][0][1];
        float m = fmaxf(a.x, c2.x);
        float u = a.y * __expf(a.x - m) + c2.y * __expf(c2.x - m);
        f0 = __expf(m0 - m) * __builtin_amdgcn_rcpf(u);
        float2 a1 = smu[pair][1][0], c1 = smu[pair][1][1];
        float m_ = fmaxf(a1.x, c1.x);
        float u_ = a1.y * __expf(a1.x - m_) + c1.y * __expf(c1.x - m_);
        f1 = __expf(m1 - m_) * __builtin_amdgcn_rcpf(u_);
    }

    // ---- att halves -> wave-private LDS (same-wave RAW, no barrier) ----
    float p0[3], p1[3];
    {
        float* ar = att_h[wave];
        #pragma unroll
        for (int c = 0; c < 3; ++c) {
            p0[c] = e0_[c] * f0;
            p1[c] = e1_[c] * f1;
            ar[c * 64 + lane]       = p0[c];
            ar[192 + c * 64 + lane] = p1[c];
        }
    }

    // ---- PV over own k-half: lane = kf*8 + dg ----
    const int kf = lane >> 3, dg = lane & 7;
    const float* vbase = vin + (size_t)b * LK * (NH * 32) + h * 32
                       + (size_t)(hh * 192 + kf) * (NH * 32) + dg * 4;
    const float* a0p = att_h[wave];
    const float* a1p = att_h[wave] + 192;
    float oa0[4] = {0.f,0.f,0.f,0.f}, oa1[4] = {0.f,0.f,0.f,0.f};
    #pragma unroll 8
    for (int k0 = 0; k0 < 192; k0 += 8) {
        float4 vv = *(const float4*)(vbase + (size_t)k0 * (NH * 32));
        float a0 = a0p[k0 + kf];
        float a1 = a1p[k0 + kf];
        oa0[0] = __builtin_fmaf(a0, vv.x, oa0[0]);
        oa0[1] = __builtin_fmaf(a0, vv.y, oa0[1]);
        oa0[2] = __builtin_fmaf(a0, vv.z, oa0[2]);
        oa0[3] = __builtin_fmaf(a0, vv.w, oa0[3]);
        oa1[0] = __builtin_fmaf(a1, vv.x, oa1[0]);
        oa1[1] = __builtin_fmaf(a1, vv.y, oa1[1]);
        oa1[2] = __builtin_fmaf(a1, vv.z, oa1[2]);
        oa1[3] = __builtin_fmaf(a1, vv.w, oa1[3]);
    }
    #pragma unroll
    for (int u = 0; u < 4; ++u) {
        oa0[u] += __shfl_xor(oa0[u], 8);
        oa0[u] += __shfl_xor(oa0[u], 16);
        oa0[u] += __shfl_xor(oa0[u], 32);
        oa1[u] += __shfl_xor(oa1[u], 8);
        oa1[u] += __shfl_xor(oa1[u], 16);
        oa1[u] += __shfl_xor(oa1[u], 32);
    }
    if (kf == 0) {
        pvp[pair][hh][0][dg] = make_float4(oa0[0], oa0[1], oa0[2], oa0[3]);
        pvp[pair][hh][1][dg] = make_float4(oa1[0], oa1[1], oa1[2], oa1[3]);
    }
    __syncthreads();   // (3)

    // ---- combine PV halves: wave w -> row w; lanes 0..7 ----
    if (lane < 8) {
        int q = q0 + wave;
        float4 xa = pvp[wave >> 1][0][wave & 1][lane];
        float4 xb = pvp[wave >> 1][1][wave & 1][lane];
        float4 o4;
        bool ok = (q < qlen);
        o4.x = ok ? (xa.x + xb.x) : 0.f;
        o4.y = ok ? (xa.y + xb.y) : 0.f;
        o4.z = ok ? (xa.z + xb.z) : 0.f;
        o4.w = ok ? (xa.w + xb.w) : 0.f;
        ((float4*)(outg + ((size_t)(b * LQ + q)) * (NH * 32) + h * 32))[lane] = o4;
    }

    // ---- deferred global att writes (coalesced, from regs) ----
    {
        float* ag = attg + ((size_t)(bh * LQ + q0 + 2 * pair)) * LK + hh * 192;
        #pragma unroll
        for (int c = 0; c < 3; ++c) ag[c * 64 + lane] = p0[c];
        ag += LK;
        #pragma unroll
        for (int c = 0; c < 3; ++c) ag[c * 64 + lane] = p1[c];
    }
}

extern "C" void kernel_launch(void* const* d_in, const int* in_sizes, int n_in,
                              void* d_out, int out_size, void* d_ws, size_t ws_size,
                              hipStream_t stream) {
    const float* q    = (const float*)d_in[0];
    const float* k    = (const float*)d_in[1];
    const float* v    = (const float*)d_in[2];
    const int*   qlen = (const int*)d_in[3];
    const int*   klen = (const int*)d_in[4];
    const float* w1   = (const float*)d_in[5];
    const float* b1   = (const float*)d_in[6];
    const float* w2   = (const float*)d_in[7];
    float* out = (float*)d_out;
    float* att = out + (size_t)BS * LQ * NH * 32;   // out: 196608, att: 2359296 floats
    float* ws  = (float*)d_ws;                      // Ek [bh][e4][k][4]: 1.5 MB

    pre_ek_kernel<<<192, 256, 0, stream>>>(k, w1, b1, ws);
    attn_kernel<<<1536, 256, 0, stream>>>(q, v, qlen, klen, w1, w2, ws, out, att);
}

// Round 9
// 98.685 us; speedup vs baseline: 1.0466x; 1.0466x over previous
//
#include <hip/hip_runtime.h>

#define NH 8
#define LQ 384
#define LK 384
#define BS 2

typedef float v2f __attribute__((ext_vector_type(2)));
__device__ __forceinline__ v2f fma2(v2f a, v2f b, v2f c) { return __builtin_elementwise_fma(a, b, c); }
__device__ __forceinline__ v2f sp(float x) { v2f r; r.x = x; r.y = x; return r; }

// ---------------- Kernel 1: Ek = exp(2*(kW+b1)), layout [bh][e4][k][4] ----------------
__global__ __launch_bounds__(256) void pre_ek_kernel(
    const float* __restrict__ kin, const float* __restrict__ w1,
    const float* __restrict__ b1, float* __restrict__ ws)
{
    __shared__ float tile[32][65];
    const int bid = blockIdx.x;
    const int bh = bid / 12, kt = bid % 12;
    const int b = bh >> 3, h = bh & 7;
    const int k0 = kt * 32;
    const int lane = threadIdx.x & 63, w = threadIdx.x >> 6;

    float w1c[32];
    const float* w1p = w1 + (size_t)(h * 64 + 32) * 64 + lane;
    #pragma unroll
    for (int d = 0; d < 32; ++d) w1c[d] = w1p[d * 64];
    const float bv = b1[h * 64 + lane];

    #pragma unroll
    for (int s = 0; s < 8; ++s) {
        int kr = w * 8 + s;
        const float* krow = kin + ((size_t)(b * LK + k0 + kr)) * (NH * 32) + h * 32;
        float acc = bv;
        #pragma unroll
        for (int d = 0; d < 32; ++d) acc = __builtin_fmaf(krow[d], w1c[d], acc);
        tile[kr][lane] = __expf(acc + acc);
    }
    __syncthreads();
    #pragma unroll
    for (int r = 0; r < 2; ++r) {
        int f = threadIdx.x + r * 256;
        int e4 = f >> 5, k32 = f & 31;
        float4 o;
        o.x = tile[k32][e4 * 4 + 0];
        o.y = tile[k32][e4 * 4 + 1];
        o.z = tile[k32][e4 * 4 + 2];
        o.w = tile[k32][e4 * 4 + 3];
        ((float4*)ws)[((size_t)(bh * 16 + e4)) * LK + k0 + k32] = o;
    }
}

// ---------------- Kernel 2: q-tile=4, wave=(pair,k-half); packed-fp32 dual-row score ----------------
// grid = 1536 (6 blocks/CU). Eq interleaved per pair -> v_pk_fma over (row0,row1).
__global__ __launch_bounds__(256) void attn_kernel(
    const float* __restrict__ qin, const float* __restrict__ vin,
    const int* __restrict__ qlens, const int* __restrict__ klens,
    const float* __restrict__ w1, const float* __restrict__ w2g,
    const float* __restrict__ ws,
    float* __restrict__ outg, float* __restrict__ attg)
{
    __shared__ __align__(16) float eqi_s[2][128];      // [pair][e*2+row] interleaved Eq
    __shared__ __align__(16) float att_h[4][2 * 192];  // wave-private att halves
    __shared__ __align__(16) float w2s[64];
    __shared__ float2 smu[2][2][2];                    // [pair][row][half] (max, sum)
    __shared__ __align__(16) float4 pvp[2][2][2][8];   // [pair][half][row][dvq]

    const int tid = threadIdx.x, wave = tid >> 6, lane = tid & 63;
    const int pair = wave >> 1, hh = wave & 1;
    const int bh = blockIdx.x / 96, tile = blockIdx.x % 96;
    const int b = bh >> 3, h = bh & 7;
    const int q0 = tile * 4;
    const int klen = klens[b], qlen = qlens[b];

    // ---- Eq: wave w computes row w (e = lane), stored interleaved by pair ----
    {
        const float* w1p = w1 + (size_t)h * 64 * 64 + lane;
        const float* qp  = qin + ((size_t)(b * LQ + q0 + wave)) * (NH * 32) + h * 32;
        float a = 0.f;
        #pragma unroll
        for (int d = 0; d < 32; ++d) a = __builtin_fmaf(qp[d], w1p[d * 64], a);
        eqi_s[pair][lane * 2 + hh] = __expf(a + a);   // 2-way bank alias: free
        if (wave == 0) w2s[lane] = w2g[h * 64 + lane];
    }
    __syncthreads();   // (1)

    // ---- score: k = hh*192 + c*64 + lane; both rows packed in v2f ----
    v2f sc[3];
    sc[0] = sp(0.f); sc[1] = sp(0.f); sc[2] = sp(0.f);
    const float4* ekq = (const float4*)ws + ((size_t)bh * 16) * LK + hh * 192 + lane;
    const v2f*   eqp = (const v2f*)eqi_s[pair];
    const float4* w2p = (const float4*)w2s;

    float4 kv[3];
    #pragma unroll
    for (int c = 0; c < 3; ++c) kv[c] = ekq[c * 64];

    #pragma unroll
    for (int e4 = 0; e4 < 16; ++e4) {
        float4 nkv[3];
        if (e4 < 15) {
            const float4* np = ekq + (size_t)(e4 + 1) * LK;
            #pragma unroll
            for (int c = 0; c < 3; ++c) nkv[c] = np[c * 64];
        }
        v2f E0 = eqp[e4 * 4 + 0];
        v2f E1 = eqp[e4 * 4 + 1];
        v2f E2 = eqp[e4 * 4 + 2];
        v2f E3 = eqp[e4 * 4 + 3];
        float4 wv = w2p[e4];
        #pragma unroll
        for (int c = 0; c < 3; ++c) {
            float4 kq = kv[c];
            v2f t0 = fma2(E0, sp(kq.x), sp(1.f));
            v2f t1 = fma2(E1, sp(kq.y), sp(1.f));
            v2f t2 = fma2(E2, sp(kq.z), sp(1.f));
            v2f t3 = fma2(E3, sp(kq.w), sp(1.f));
            v2f p12 = t0 * t1, p34 = t2 * t3;
            v2f n12 = fma2(sp(wv.y), t0, sp(wv.x) * t1);
            v2f n34 = fma2(sp(wv.w), t2, sp(wv.z) * t3);
            v2f num = fma2(n34, p12, n12 * p34);
            v2f den = p12 * p34;
            v2f r;
            r.x = __builtin_amdgcn_rcpf(den.x);
            r.y = __builtin_amdgcn_rcpf(den.y);
            sc[c] = fma2(num, r, sc[c]);
        }
        if (e4 < 15) {
            #pragma unroll
            for (int c = 0; c < 3; ++c) kv[c] = nkv[c];
        }
    }

    // ---- local softmax stats + single exchange barrier ----
    float s0_[3], s1_[3];
    float m0 = -3.4e38f, m1 = -3.4e38f;
    #pragma unroll
    for (int c = 0; c < 3; ++c) {
        int kk = hh * 192 + c * 64 + lane;
        s0_[c] = (kk < klen) ? -2.0f * sc[c].x : -3.4e38f;
        s1_[c] = (kk < klen) ? -2.0f * sc[c].y : -3.4e38f;
        m0 = fmaxf(m0, s0_[c]);
        m1 = fmaxf(m1, s1_[c]);
    }
    #pragma unroll
    for (int off = 32; off >= 1; off >>= 1) {
        m0 = fmaxf(m0, __shfl_xor(m0, off));
        m1 = fmaxf(m1, __shfl_xor(m1, off));
    }
    float e0_[3], e1_[3];
    float u0 = 0.f, u1 = 0.f;
    #pragma unroll
    for (int c = 0; c < 3; ++c) {
        int kk = hh * 192 + c * 64 + lane;
        e0_[c] = (kk < klen) ? __expf(s0_[c] - m0) : 0.f;
        e1_[c] = (kk < klen) ? __expf(s1_[c] - m1) : 0.f;
        u0 += e0_[c];
        u1 += e1_[c];
    }
    #pragma unroll
    for (int off = 32; off >= 1; off >>= 1) {
        u0 += __shfl_xor(u0, off);
        u1 += __shfl_xor(u1, off);
    }
    if (lane == 0) {
        smu[pair][0][hh] = make_float2(m0, u0);
        smu[pair][1][hh] = make_float2(m1, u1);
    }
    __syncthreads();   // (2)
    float f0, f1;
    {
        float2 a = smu[pair][0][0], c2 = smu[pair][0][1];
        float m = fmaxf(a.x, c2.x);
        float u = a.y * __expf(a.x - m) + c2.y * __expf(c2.x - m);
        f0 = __expf(m0 - m) * __builtin_amdgcn_rcpf(u);
        float2 a1 = smu[pair][1][0], c1 = smu[pair][1][1];
        float m_ = fmaxf(a1.x, c1.x);
        float u_ = a1.y * __expf(a1.x - m_) + c1.y * __expf(c1.x - m_);
        f1 = __expf(m1 - m_) * __builtin_amdgcn_rcpf(u_);
    }

    // ---- att halves -> wave-private LDS (same-wave RAW, no barrier) ----
    float p0[3], p1[3];
    {
        float* ar = att_h[wave];
        #pragma unroll
        for (int c = 0; c < 3; ++c) {
            p0[c] = e0_[c] * f0;
            p1[c] = e1_[c] * f1;
            ar[c * 64 + lane]       = p0[c];
            ar[192 + c * 64 + lane] = p1[c];
        }
    }

    // ---- PV over own k-half: lane = kf*8 + dg ----
    const int kf = lane >> 3, dg = lane & 7;
    const float* vbase = vin + (size_t)b * LK * (NH * 32) + h * 32
                       + (size_t)(hh * 192 + kf) * (NH * 32) + dg * 4;
    const float* a0p = att_h[wave];
    const float* a1p = att_h[wave] + 192;
    float oa0[4] = {0.f,0.f,0.f,0.f}, oa1[4] = {0.f,0.f,0.f,0.f};
    #pragma unroll 8
    for (int k0 = 0; k0 < 192; k0 += 8) {
        float4 vv = *(const float4*)(vbase + (size_t)k0 * (NH * 32));
        float a0 = a0p[k0 + kf];
        float a1 = a1p[k0 + kf];
        oa0[0] = __builtin_fmaf(a0, vv.x, oa0[0]);
        oa0[1] = __builtin_fmaf(a0, vv.y, oa0[1]);
        oa0[2] = __builtin_fmaf(a0, vv.z, oa0[2]);
        oa0[3] = __builtin_fmaf(a0, vv.w, oa0[3]);
        oa1[0] = __builtin_fmaf(a1, vv.x, oa1[0]);
        oa1[1] = __builtin_fmaf(a1, vv.y, oa1[1]);
        oa1[2] = __builtin_fmaf(a1, vv.z, oa1[2]);
        oa1[3] = __builtin_fmaf(a1, vv.w, oa1[3]);
    }
    #pragma unroll
    for (int u = 0; u < 4; ++u) {
        oa0[u] += __shfl_xor(oa0[u], 8);
        oa0[u] += __shfl_xor(oa0[u], 16);
        oa0[u] += __shfl_xor(oa0[u], 32);
        oa1[u] += __shfl_xor(oa1[u], 8);
        oa1[u] += __shfl_xor(oa1[u], 16);
        oa1[u] += __shfl_xor(oa1[u], 32);
    }
    if (kf == 0) {
        pvp[pair][hh][0][dg] = make_float4(oa0[0], oa0[1], oa0[2], oa0[3]);
        pvp[pair][hh][1][dg] = make_float4(oa1[0], oa1[1], oa1[2], oa1[3]);
    }
    __syncthreads();   // (3)

    // ---- combine PV halves: wave w -> row w; lanes 0..7 ----
    if (lane < 8) {
        int q = q0 + wave;
        float4 xa = pvp[wave >> 1][0][wave & 1][lane];
        float4 xb = pvp[wave >> 1][1][wave & 1][lane];
        float4 o4;
        bool ok = (q < qlen);
        o4.x = ok ? (xa.x + xb.x) : 0.f;
        o4.y = ok ? (xa.y + xb.y) : 0.f;
        o4.z = ok ? (xa.z + xb.z) : 0.f;
        o4.w = ok ? (xa.w + xb.w) : 0.f;
        ((float4*)(outg + ((size_t)(b * LQ + q)) * (NH * 32) + h * 32))[lane] = o4;
    }

    // ---- deferred global att writes (coalesced, from regs) ----
    {
        float* ag = attg + ((size_t)(bh * LQ + q0 + 2 * pair)) * LK + hh * 192;
        #pragma unroll
        for (int c = 0; c < 3; ++c) ag[c * 64 + lane] = p0[c];
        ag += LK;
        #pragma unroll
        for (int c = 0; c < 3; ++c) ag[c * 64 + lane] = p1[c];
    }
}

extern "C" void kernel_launch(void* const* d_in, const int* in_sizes, int n_in,
                              void* d_out, int out_size, void* d_ws, size_t ws_size,
                              hipStream_t stream) {
    const float* q    = (const float*)d_in[0];
    const float* k    = (const float*)d_in[1];
    const float* v    = (const float*)d_in[2];
    const int*   qlen = (const int*)d_in[3];
    const int*   klen = (const int*)d_in[4];
    const float* w1   = (const float*)d_in[5];
    const float* b1   = (const float*)d_in[6];
    const float* w2   = (const float*)d_in[7];
    float* out = (float*)d_out;
    float* att = out + (size_t)BS * LQ * NH * 32;   // out: 196608, att: 2359296 floats
    float* ws  = (float*)d_ws;                      // Ek [bh][e4][k][4]: 1.5 MB

    pre_ek_kernel<<<192, 256, 0, stream>>>(k, w1, b1, ws);
    attn_kernel<<<1536, 256, 0, stream>>>(q, v, qlen, klen, w1, w2, ws, out, att);
}

// Round 10
// 97.693 us; speedup vs baseline: 1.0573x; 1.0102x over previous
//
#include <hip/hip_runtime.h>

#define NH 8
#define LQ 384
#define LK 384
#define BS 2

typedef float v2f __attribute__((ext_vector_type(2)));
__device__ __forceinline__ v2f fma2(v2f a, v2f b, v2f c) { return __builtin_elementwise_fma(a, b, c); }
__device__ __forceinline__ v2f sp(float x) { v2f r; r.x = x; r.y = x; return r; }

// ---------------- Kernel 1: Ek = exp(2*(kW+b1)), layout [bh][e4][k][4] ----------------
// grid = 384: bh = bid/24, 16-k tile. 1.5 blocks/CU.
__global__ __launch_bounds__(256) void pre_ek_kernel(
    const float* __restrict__ kin, const float* __restrict__ w1,
    const float* __restrict__ b1, float* __restrict__ ws)
{
    __shared__ float tile[16][65];
    const int bid = blockIdx.x;
    const int bh = bid / 24, kt = bid % 24;
    const int b = bh >> 3, h = bh & 7;
    const int k0 = kt * 16;
    const int tid = threadIdx.x;
    const int lane = tid & 63, w = tid >> 6;

    float w1c[32];
    const float* w1p = w1 + (size_t)(h * 64 + 32) * 64 + lane;
    #pragma unroll
    for (int d = 0; d < 32; ++d) w1c[d] = w1p[d * 64];
    const float bv = b1[h * 64 + lane];

    #pragma unroll
    for (int s = 0; s < 4; ++s) {
        int kr = w * 4 + s;
        const float* krow = kin + ((size_t)(b * LK + k0 + kr)) * (NH * 32) + h * 32;
        float acc = bv;
        #pragma unroll
        for (int d = 0; d < 32; ++d) acc = __builtin_fmaf(krow[d], w1c[d], acc);
        tile[kr][lane] = __expf(acc + acc);
    }
    __syncthreads();
    {
        int e4 = tid >> 4, k16 = tid & 15;
        float4 o;
        o.x = tile[k16][e4 * 4 + 0];
        o.y = tile[k16][e4 * 4 + 1];
        o.z = tile[k16][e4 * 4 + 2];
        o.w = tile[k16][e4 * 4 + 3];
        ((float4*)ws)[((size_t)(bh * 16 + e4)) * LK + k0 + k16] = o;
    }
}

// ---------------- Kernel 2: packed dual-row score + deferred-normalization PV ----------------
// grid = 1536 (6 blocks/CU): bh = blk/96, q-tile of 4; wave=(pair,k-half).
__global__ __launch_bounds__(256) void attn_kernel(
    const float* __restrict__ qin, const float* __restrict__ vin,
    const int* __restrict__ qlens, const int* __restrict__ klens,
    const float* __restrict__ w1, const float* __restrict__ w2g,
    const float* __restrict__ ws,
    float* __restrict__ outg, float* __restrict__ attg)
{
    __shared__ __align__(16) float eqi_s[2][128];      // [pair][e*2+row] interleaved Eq
    __shared__ __align__(16) float att_h[4][2 * 192];  // wave-private e_ halves
    __shared__ __align__(16) float w2s[64];
    __shared__ float2 smu[2][2][2];                    // [pair][row][half] (max, sum)
    __shared__ __align__(16) float4 pvp[2][2][2][8];   // [pair][half][row][dvq]

    const int tid = threadIdx.x, wave = tid >> 6, lane = tid & 63;
    const int pair = wave >> 1, hh = wave & 1;
    const int bh = blockIdx.x / 96, tile = blockIdx.x % 96;
    const int b = bh >> 3, h = bh & 7;
    const int q0 = tile * 4;
    const int klen = klens[b], qlen = qlens[b];

    // ---- Eq: wave w computes row w (e = lane), interleaved by pair ----
    {
        const float* w1p = w1 + (size_t)h * 64 * 64 + lane;
        const float* qp  = qin + ((size_t)(b * LQ + q0 + wave)) * (NH * 32) + h * 32;
        float a = 0.f;
        #pragma unroll
        for (int d = 0; d < 32; ++d) a = __builtin_fmaf(qp[d], w1p[d * 64], a);
        eqi_s[pair][lane * 2 + hh] = __expf(a + a);
        if (wave == 0) w2s[lane] = w2g[h * 64 + lane];
    }
    __syncthreads();   // (1)

    // ---- score: k = hh*192 + c*64 + lane; depth-2 kv prefetch ----
    v2f sc[3];
    sc[0] = sp(0.f); sc[1] = sp(0.f); sc[2] = sp(0.f);
    const float4* ekq = (const float4*)ws + ((size_t)bh * 16) * LK + hh * 192 + lane;
    const v2f*   eqp = (const v2f*)eqi_s[pair];
    const float4* w2p = (const float4*)w2s;

    float4 kva[3], kvb[3];
    #pragma unroll
    for (int c = 0; c < 3; ++c) kva[c] = ekq[c * 64];
    #pragma unroll
    for (int c = 0; c < 3; ++c) kvb[c] = ekq[LK + c * 64];

    #pragma unroll
    for (int e4 = 0; e4 < 16; ++e4) {
        float4* cur = (e4 & 1) ? kvb : kva;
        float4 kq0 = cur[0], kq1 = cur[1], kq2 = cur[2];
        if (e4 < 14) {
            const float4* np = ekq + (size_t)(e4 + 2) * LK;
            cur[0] = np[0]; cur[1] = np[64]; cur[2] = np[128];
        }
        v2f E0 = eqp[e4 * 4 + 0];
        v2f E1 = eqp[e4 * 4 + 1];
        v2f E2 = eqp[e4 * 4 + 2];
        v2f E3 = eqp[e4 * 4 + 3];
        float4 wv = w2p[e4];
        float4 kqs[3] = {kq0, kq1, kq2};
        #pragma unroll
        for (int c = 0; c < 3; ++c) {
            float4 kq = kqs[c];
            v2f t0 = fma2(E0, sp(kq.x), sp(1.f));
            v2f t1 = fma2(E1, sp(kq.y), sp(1.f));
            v2f t2 = fma2(E2, sp(kq.z), sp(1.f));
            v2f t3 = fma2(E3, sp(kq.w), sp(1.f));
            v2f p12 = t0 * t1, p34 = t2 * t3;
            v2f n12 = fma2(sp(wv.y), t0, sp(wv.x) * t1);
            v2f n34 = fma2(sp(wv.w), t2, sp(wv.z) * t3);
            v2f num = fma2(n34, p12, n12 * p34);
            v2f den = p12 * p34;
            v2f r;
            r.x = __builtin_amdgcn_rcpf(den.x);
            r.y = __builtin_amdgcn_rcpf(den.y);
            sc[c] = fma2(num, r, sc[c]);
        }
    }

    // ---- wave-local softmax stats ----
    float s0_[3], s1_[3];
    float m0 = -3.4e38f, m1 = -3.4e38f;
    #pragma unroll
    for (int c = 0; c < 3; ++c) {
        int kk = hh * 192 + c * 64 + lane;
        s0_[c] = (kk < klen) ? -2.0f * sc[c].x : -3.4e38f;
        s1_[c] = (kk < klen) ? -2.0f * sc[c].y : -3.4e38f;
        m0 = fmaxf(m0, s0_[c]);
        m1 = fmaxf(m1, s1_[c]);
    }
    #pragma unroll
    for (int off = 32; off >= 1; off >>= 1) {
        m0 = fmaxf(m0, __shfl_xor(m0, off));
        m1 = fmaxf(m1, __shfl_xor(m1, off));
    }
    float e0_[3], e1_[3];
    float u0 = 0.f, u1 = 0.f;
    #pragma unroll
    for (int c = 0; c < 3; ++c) {
        int kk = hh * 192 + c * 64 + lane;
        e0_[c] = (kk < klen) ? __expf(s0_[c] - m0) : 0.f;
        e1_[c] = (kk < klen) ? __expf(s1_[c] - m1) : 0.f;
        u0 += e0_[c];
        u1 += e1_[c];
    }
    #pragma unroll
    for (int off = 32; off >= 1; off >>= 1) {
        u0 += __shfl_xor(u0, off);
        u1 += __shfl_xor(u1, off);
    }
    if (lane == 0) {
        smu[pair][0][hh] = make_float2(m0, u0);
        smu[pair][1][hh] = make_float2(m1, u1);
    }
    // e_ halves -> wave-private LDS (same-wave RAW, no barrier)
    {
        float* ar = att_h[wave];
        #pragma unroll
        for (int c = 0; c < 3; ++c) {
            ar[c * 64 + lane]       = e0_[c];
            ar[192 + c * 64 + lane] = e1_[c];
        }
    }

    // ---- PV with UNNORMALIZED e_ weights (normalization deferred past the exchange) ----
    const int kf = lane >> 3, dg = lane & 7;
    const float* vbase = vin + (size_t)b * LK * (NH * 32) + h * 32
                       + (size_t)(hh * 192 + kf) * (NH * 32) + dg * 4;
    const float* a0p = att_h[wave];
    const float* a1p = att_h[wave] + 192;
    float oa0[4] = {0.f,0.f,0.f,0.f}, oa1[4] = {0.f,0.f,0.f,0.f};
    float4 vbuf[2];
    vbuf[0] = *(const float4*)(vbase);
    vbuf[1] = *(const float4*)(vbase + (size_t)8 * (NH * 32));
    #pragma unroll
    for (int i = 0; i < 24; ++i) {
        float4 vv = vbuf[i & 1];
        if (i < 22) vbuf[i & 1] = *(const float4*)(vbase + (size_t)((i + 2) * 8) * (NH * 32));
        int k0 = i * 8;
        float a0 = a0p[k0 + kf];
        float a1 = a1p[k0 + kf];
        oa0[0] = __builtin_fmaf(a0, vv.x, oa0[0]);
        oa0[1] = __builtin_fmaf(a0, vv.y, oa0[1]);
        oa0[2] = __builtin_fmaf(a0, vv.z, oa0[2]);
        oa0[3] = __builtin_fmaf(a0, vv.w, oa0[3]);
        oa1[0] = __builtin_fmaf(a1, vv.x, oa1[0]);
        oa1[1] = __builtin_fmaf(a1, vv.y, oa1[1]);
        oa1[2] = __builtin_fmaf(a1, vv.z, oa1[2]);
        oa1[3] = __builtin_fmaf(a1, vv.w, oa1[3]);
    }
    #pragma unroll
    for (int u = 0; u < 4; ++u) {
        oa0[u] += __shfl_xor(oa0[u], 8);
        oa0[u] += __shfl_xor(oa0[u], 16);
        oa0[u] += __shfl_xor(oa0[u], 32);
        oa1[u] += __shfl_xor(oa1[u], 8);
        oa1[u] += __shfl_xor(oa1[u], 16);
        oa1[u] += __shfl_xor(oa1[u], 32);
    }
    __syncthreads();   // (2) smu written long ago by all waves; near-free sync

    // ---- normalization factors (cross-half merge) ----
    float f0, f1;
    {
        float2 a = smu[pair][0][0], c2 = smu[pair][0][1];
        float m = fmaxf(a.x, c2.x);
        float u = a.y * __expf(a.x - m) + c2.y * __expf(c2.x - m);
        f0 = __expf(m0 - m) * __builtin_amdgcn_rcpf(u);
        float2 a1 = smu[pair][1][0], c1 = smu[pair][1][1];
        float m_ = fmaxf(a1.x, c1.x);
        float u_ = a1.y * __expf(a1.x - m_) + c1.y * __expf(c1.x - m_);
        f1 = __expf(m1 - m_) * __builtin_amdgcn_rcpf(u_);
    }

    if (kf == 0) {   // lanes 0..7: scale reduced partials by this half's factor
        pvp[pair][hh][0][dg] = make_float4(oa0[0] * f0, oa0[1] * f0, oa0[2] * f0, oa0[3] * f0);
        pvp[pair][hh][1][dg] = make_float4(oa1[0] * f1, oa1[1] * f1, oa1[2] * f1, oa1[3] * f1);
    }
    __syncthreads();   // (3)

    // ---- combine PV halves: wave w -> row w; lanes 0..7 ----
    if (lane < 8) {
        int q = q0 + wave;
        float4 xa = pvp[wave >> 1][0][wave & 1][lane];
        float4 xb = pvp[wave >> 1][1][wave & 1][lane];
        float4 o4;
        bool ok = (q < qlen);
        o4.x = ok ? (xa.x + xb.x) : 0.f;
        o4.y = ok ? (xa.y + xb.y) : 0.f;
        o4.z = ok ? (xa.z + xb.z) : 0.f;
        o4.w = ok ? (xa.w + xb.w) : 0.f;
        ((float4*)(outg + ((size_t)(b * LQ + q)) * (NH * 32) + h * 32))[lane] = o4;
    }

    // ---- att global writes: p = e_ * f (coalesced, from regs) ----
    {
        float* ag = attg + ((size_t)(bh * LQ + q0 + 2 * pair)) * LK + hh * 192;
        #pragma unroll
        for (int c = 0; c < 3; ++c) ag[c * 64 + lane] = e0_[c] * f0;
        ag += LK;
        #pragma unroll
        for (int c = 0; c < 3; ++c) ag[c * 64 + lane] = e1_[c] * f1;
    }
}

extern "C" void kernel_launch(void* const* d_in, const int* in_sizes, int n_in,
                              void* d_out, int out_size, void* d_ws, size_t ws_size,
                              hipStream_t stream) {
    const float* q    = (const float*)d_in[0];
    const float* k    = (const float*)d_in[1];
    const float* v    = (const float*)d_in[2];
    const int*   qlen = (const int*)d_in[3];
    const int*   klen = (const int*)d_in[4];
    const float* w1   = (const float*)d_in[5];
    const float* b1   = (const float*)d_in[6];
    const float* w2   = (const float*)d_in[7];
    float* out = (float*)d_out;
    float* att = out + (size_t)BS * LQ * NH * 32;   // out: 196608, att: 2359296 floats
    float* ws  = (float*)d_ws;                      // Ek [bh][e4][k][4]: 1.5 MB

    pre_ek_kernel<<<384, 256, 0, stream>>>(k, w1, b1, ws);
    attn_kernel<<<1536, 256, 0, stream>>>(q, v, qlen, klen, w1, w2, ws, out, att);
}